// Round 20
// baseline (348.619 us; speedup 1.0000x reference)
//
#include <hip/hip_runtime.h>
#include <hip/hip_bf16.h>

// Problem constants
#define NB   4
#define CIN  64
#define COUT 128
#define SDIM 512
#define DIM  48
#define SP   (DIM*DIM*DIM)   // 110592
#define TAPS 27
#define KTOT (CIN*TAPS)      // 1728

// ---- small-param layout (float offsets at base of ws) ----
#define WS_S1P 0                         // [NB*CIN]       1+scale
#define WS_SH  (WS_S1P + NB*CIN)         // [NB*CIN]       shift
#define WS_KM  (WS_SH + NB*CIN)          // [NB*CIN*TAPS]  kmod
// ---- fast path byte offsets ----
#define XPB_OFF   32768ull                        // padded mod x (bf16 channel-last), 64 MB
#define XPB_BYTES (4ull*125000ull*64ull*2ull)     // 64,000,000
#define WSBF_OFF  (XPB_OFF + XPB_BYTES)
#define WSBF_BYTES ((size_t)NB*27*8*128*8*2)      // 1,769,472

typedef __attribute__((ext_vector_type(4))) float  f32x4;
typedef __attribute__((ext_vector_type(8))) short  short8;
typedef __attribute__((ext_vector_type(8))) unsigned short u16x8;

__device__ __forceinline__ void gld16(const void* g, void* l) {
    __builtin_amdgcn_global_load_lds(
        (const __attribute__((address_space(1))) void*)g,
        (__attribute__((address_space(3))) void*)l, 16, 0, 0);
}

// ---------------------------------------------------------------------------
// Kernel A: style dot products. One wave per row. float4-vectorized loads.
// ---------------------------------------------------------------------------
__global__ void modparams_kernel(const float* __restrict__ style,
                                 const float* __restrict__ w_scale, const float* __restrict__ b_scale,
                                 const float* __restrict__ w_shift, const float* __restrict__ b_shift,
                                 const float* __restrict__ w_kmod,  const float* __restrict__ b_kmod,
                                 float* __restrict__ ws) {
    const int ROWS = 2 * CIN + CIN * TAPS;  // 1856
    int gwave = (blockIdx.x * blockDim.x + threadIdx.x) >> 6;
    int lane  = threadIdx.x & 63;
    if (gwave >= NB * ROWS) return;
    int b = gwave / ROWS;
    int r = gwave % ROWS;

    const float* srow = style + b * SDIM;
    const float* mrow;
    float bias, add = 0.f;
    float* dst;
    if (r < CIN) {
        mrow = w_scale + r * SDIM; bias = b_scale[r];
        dst = ws + WS_S1P + b * CIN + r; add = 1.f;          // store (1+scale)
    } else if (r < 2 * CIN) {
        int c = r - CIN;
        mrow = w_shift + c * SDIM; bias = b_shift[c];
        dst = ws + WS_SH + b * CIN + c;
    } else {
        int t = r - 2 * CIN;
        mrow = w_kmod + t * SDIM; bias = b_kmod[t];
        dst = ws + WS_KM + b * (CIN * TAPS) + t;
    }

    const float4* s4 = (const float4*)srow;
    const float4* m4 = (const float4*)mrow;
    float acc = 0.f;
    #pragma unroll
    for (int k4 = 0; k4 < 2; ++k4) {
        float4 sv = s4[lane + k4 * 64];
        float4 mv = m4[lane + k4 * 64];
        acc += sv.x * mv.x + sv.y * mv.y + sv.z * mv.z + sv.w * mv.w;
    }
    #pragma unroll
    for (int off = 32; off; off >>= 1) acc += __shfl_down(acc, off);
    if (lane == 0) *dst = acc + bias + add;
}

// ---------------------------------------------------------------------------
// WSBF2[(((b*27+tau)*8 + s)*128 + o)*8 + j] = bf16(weight[o, c=s*8+j, tau] *
//                                                  (1 + kmod[b, c, tau]))
// ---------------------------------------------------------------------------
__global__ void build_wsbf2_kernel(const float* __restrict__ weight, const float* __restrict__ ws,
                                   unsigned short* __restrict__ wsbf) {
    int d = blockIdx.x * blockDim.x + threadIdx.x;
    if (d >= NB * 27 * 8 * 128 * 8) return;
    int j   = d & 7;
    int o   = (d >> 3) & 127;
    int s   = (d >> 10) & 7;
    int rem = d >> 13;
    int tau = rem % 27;
    int b   = rem / 27;
    int c   = s * 8 + j;
    float wm = weight[(o * CIN + c) * TAPS + tau] * (1.f + ws[WS_KM + b * KTOT + c * TAPS + tau]);
    __hip_bfloat16 h = __float2bfloat16(wm);
    wsbf[d] = *(unsigned short*)&h;
}

// ---------------------------------------------------------------------------
// Pad + modulate + transpose to channel-last bf16: xpb[b][pz][py][px][c]
// float4-vectorized x reads.
// ---------------------------------------------------------------------------
__global__ __launch_bounds__(256) void pad_kernel(const float* __restrict__ x,
                                                  const float* __restrict__ ws,
                                                  unsigned short* __restrict__ xpb) {
    __shared__ unsigned short lxm[48 * 72];   // [w][c], row stride 144B (16B-aligned)
    int bid = blockIdx.x;
    int py = bid % 50;
    int pz = (bid / 50) % 50;
    int b  = bid / 2500;
    int t = threadIdx.x;
    bool interior = (pz >= 1 && pz <= 48 && py >= 1 && py <= 48);
    if (interior) {
        int z = pz - 1, y = py - 1;
        const float* xr = x + (size_t)b * CIN * SP + (size_t)z * (DIM*DIM) + y * DIM;
        #pragma unroll
        for (int it = 0; it < 3; ++it) {
            int u = it * 256 + t;                 // 768 float4 units
            int c  = u / 12;
            int w4 = (u - c * 12) * 4;
            float4 v = *(const float4*)(xr + (size_t)c * SP + w4);
            float s1 = ws[WS_S1P + b * CIN + c];
            float sh = ws[WS_SH  + b * CIN + c];
            float m0 = v.x * s1 + sh, m1 = v.y * s1 + sh;
            float m2 = v.z * s1 + sh, m3 = v.w * s1 + sh;
            __hip_bfloat16 h0 = __float2bfloat16(m0);
            __hip_bfloat16 h1 = __float2bfloat16(m1);
            __hip_bfloat16 h2 = __float2bfloat16(m2);
            __hip_bfloat16 h3 = __float2bfloat16(m3);
            lxm[(w4 + 0) * 72 + c] = *(unsigned short*)&h0;
            lxm[(w4 + 1) * 72 + c] = *(unsigned short*)&h1;
            lxm[(w4 + 2) * 72 + c] = *(unsigned short*)&h2;
            lxm[(w4 + 3) * 72 + c] = *(unsigned short*)&h3;
        }
    }
    __syncthreads();
    unsigned short* dst = xpb + (size_t)b * 8000000ull + ((size_t)pz * 2500 + py * 50) * 64;
    #pragma unroll
    for (int it = 0; it < 2; ++it) {
        int i8 = it * 256 + t;
        if (i8 < 400) {
            int w  = i8 >> 3;          // padded px
            int c8 = (i8 & 7) * 8;
            u16x8 v = {};
            if (interior && w >= 1 && w <= 48)
                v = *(const u16x8*)&lxm[(w - 1) * 72 + c8];
            *(u16x8*)(dst + i8 * 8) = v;
        }
    }
}

// ---------------------------------------------------------------------------
// Conv v18 (= R19 with CORRECT ch1 global addressing): 512 thr, 4z x 8y x 8x,
// pinned-A asm pipeline, cross-tap B, zero-VALU LDS addressing, DUAL-SOURCE B:
//   ch0 half (32 ch) from LDS halo (38.4 KB, pos-major XOR, ds offset imm)
//   ch1 half (32 ch) direct from global (L2-hot xpb), prefetched 1 tap ahead.
// ch1 global addresses use GLOBAL strides (2500/50/1 positions): per-nf base
// pointers xw1p[nf] + compile-time byte delta DLTGB(tap). imm offsets all 0.
// vmcnt: 12 loads/tap (8 A + 4 B-ch1); steady-state wait vmcnt(12).
// ---------------------------------------------------------------------------
#define HALOPOS 600            // 6*10*10
#define BH_CHUNKS (HALOPOS*4)  // 2400 16B-chunks (ch0 half only)

#define GLD16R(dst, p, OFF)                                                    \
    asm volatile("global_load_dwordx4 %0, %1, off offset:" #OFF                \
                 : "=v"(dst) : "v"(p) : "memory")

#define ISSUEA(buf, tap_) do {                                                 \
    const unsigned short* _p0 = wA + (size_t)(tap_) * 8192;                    \
    const unsigned short* _p1 = _p0 + 4096;                                    \
    GLD16R(buf[0], _p0, 0);   GLD16R(buf[1], _p0, 256);                        \
    GLD16R(buf[2], _p0, 512); GLD16R(buf[3], _p0, 768);                        \
    GLD16R(buf[4], _p1, 0);   GLD16R(buf[5], _p1, 256);                        \
    GLD16R(buf[6], _p1, 512); GLD16R(buf[7], _p1, 768);                        \
} while (0)

// tap delta within halo position space (compile-time when unrolled)
#define DLT(t_) (((t_) / 9) * 100 + (((t_) / 3) % 3) * 10 + ((t_) % 3))
// tap delta in GLOBAL xpb byte space: (kd*2500 + kh*50 + kw) positions * 128 B
#define DLTGB(t_) ((((t_) / 9) * 2500 + (((t_) / 3) % 3) * 50 + ((t_) % 3)) * 128)

// ch1 B frags for tap t_ straight from global (correct global strides).
#define ISSUEB1G(buf, tap_) do {                                               \
    _Pragma("unroll")                                                          \
    for (int nf = 0; nf < 4; ++nf) {                                           \
        const char* _pg = (const char*)xw1p[nf] + DLTGB(tap_);                 \
        GLD16R(buf[nf], _pg, 0);                                               \
    }                                                                          \
} while (0)

// ch0 B frags for tap t_ from LDS, zero-VALU: byte = bb0[D&3] + D*64.
#define BREADX(dst, t_) do {                                                   \
    _Pragma("unroll")                                                          \
    for (int nf = 0; nf < 4; ++nf) {                                           \
        const int D = DLT(t_) + nf * 20;                                       \
        dst[nf] = *(const short8*)((const char*)Bh + bb0[D & 3] + D * 64);     \
    }                                                                          \
} while (0)

// one tap: bcur = ch0 LDS frags (read last tap); bGc = ch1 global frags
// (issued last tap). Loads for t+1 issue first; wait drains tap-t's 12.
#define TAPP(curA, nxtA, bcur, bnxt, bGc, bGn, t_) do {                        \
    if ((t_) < 26) {                                                           \
        ISSUEA(nxtA, (t_) + 1);                                                \
        ISSUEB1G(bGn, (t_) + 1);                                               \
        asm volatile("s_waitcnt vmcnt(12)" ::: "memory");                      \
    } else {                                                                   \
        asm volatile("s_waitcnt vmcnt(0)" ::: "memory");                       \
    }                                                                          \
    __builtin_amdgcn_sched_barrier(0);                                         \
    _Pragma("unroll")                                                          \
    for (int mf = 0; mf < 4; ++mf)                                             \
        _Pragma("unroll")                                                      \
        for (int nf = 0; nf < 4; ++nf)                                         \
            acc[mf][nf] = __builtin_amdgcn_mfma_f32_16x16x32_bf16(             \
                curA[mf], bcur[nf], acc[mf][nf], 0, 0, 0);                     \
    if ((t_) < 26) BREADX(bnxt, (t_) + 1);   /* next tap ch0, early */         \
    _Pragma("unroll")                                                          \
    for (int mf = 0; mf < 4; ++mf)                                             \
        _Pragma("unroll")                                                      \
        for (int nf = 0; nf < 4; ++nf)                                         \
            acc[mf][nf] = __builtin_amdgcn_mfma_f32_16x16x32_bf16(             \
                curA[4 + mf], bGc[nf], acc[mf][nf], 0, 0, 0);                  \
} while (0)

__global__ __launch_bounds__(512, 2) void conv_fast18_kernel(
    const unsigned short* __restrict__ xpb,
    const unsigned short* __restrict__ wsbf,
    const float* __restrict__ bias,
    float* __restrict__ out)
{
    __shared__ unsigned short Bh[HALOPOS * 32];   // 38,400 B (ch0 half)

    const int t    = threadIdx.x;
    const int lane = t & 63;
    const int wid  = t >> 6;        // 0..7
    const int wz   = wid & 3;       // z-plane
    const int mh   = wid >> 2;      // M half (0/1)

    // XCD-aware bijective swizzle: 1728 = 8 * 216
    int bid0 = blockIdx.x;
    int bid  = (bid0 & 7) * 216 + (bid0 >> 3);
    int tile = bid % 432;
    int b    = bid / 432;
    int tx = tile % 6;
    int ty = (tile / 6) % 6;
    int tz = tile / 36;             // 0..11
    int x0 = tx * 8, y0 = ty * 8, z0 = tz * 4;

    const unsigned short* xb = xpb + (size_t)b * 8000000ull;
    const unsigned short* wb = wsbf + (size_t)b * (27 * 8 * 128 * 8);

    const int col  = lane & 15;
    const int krow = lane >> 4;   // 0..3
    const int cy   = col >> 3;    // 0..1
    const int cx   = col & 7;     // 0..7
    const int pbase = wz * 100 + cy * 10 + cx;

    // per-lane A base (shorts): slot = ch*4 + krow, o = mh*64 + mf*16 + col
    const unsigned short* wA = wb + (size_t)(krow * 128 + mh * 64 + col) * 8;

    // per-lane ch1 global bases, GLOBAL strides: one per nf (y += nf*2)
    const unsigned short* xw1p[4];
    #pragma unroll
    for (int nf = 0; nf < 4; ++nf)
        xw1p[nf] = xb
            + ((size_t)(z0 + wz) * 2500
               + (size_t)(y0 + cy + nf * 2) * 50
               + (x0 + cx)) * 64
            + (4 + krow) * 8;

    // precomputed ch0 LDS base byte-offsets: row = 64 B, 4 chunk slots
    unsigned bb0[4];
    #pragma unroll
    for (int j = 0; j < 4; ++j) {
        int pj = (pbase + j) & 3;
        bb0[j] = (unsigned)(pbase * 64 + ((krow ^ pj) << 4));
    }

    f32x4 acc[4][4] = {};
    short8 a0[8], a1[8];
    short8 bX[4], bY[4], bGa[4], bGb[4];

    ISSUEA(a0, 0);      // tap-0 A in flight
    ISSUEB1G(bGa, 0);   // tap-0 ch1 B in flight (drained by barrier)

    // ---- stage ch0 halo once: gld16, pre-swizzled global source ----
    #pragma unroll
    for (int it = 0; it < 5; ++it) {
        int i = it * 512 + t;
        if (i < BH_CHUNKS) {
            int pidx = i >> 2;
            int slot = i & 3;
            int hx = pidx % 10;
            int hy = (pidx / 10) % 10;
            int hz = pidx / 100;
            int srcslot = slot ^ (pidx & 3);
            const unsigned short* g = xb
                + ((size_t)((z0 + hz) * 2500 + (y0 + hy) * 50 + (x0 + hx))) * 64
                + srcslot * 8;
            gld16(g, &Bh[i * 8]);
        }
    }
    __syncthreads();   // halo + tap-0 A + tap-0 ch1-B staged (vmcnt drained)

    BREADX(bX, 0);   // prologue: tap-0 ch0 fragments

    #pragma unroll
    for (int tp = 0; tp < 26; tp += 2) {
        TAPP(a0, a1, bX, bY, bGa, bGb, tp);
        TAPP(a1, a0, bY, bX, bGb, bGa, tp + 1);
    }
    TAPP(a0, a1, bX, bY, bGa, bGb, 26);

    // ---- epilogue: + bias, store ----
    int z  = z0 + wz;
    int xx = x0 + cx;
    #pragma unroll
    for (int mf = 0; mf < 4; ++mf) {
        f32x4 bv = *(const f32x4*)&bias[mh * 64 + mf * 16 + krow * 4];
        #pragma unroll
        for (int nf = 0; nf < 4; ++nf) {
            int y = y0 + nf * 2 + cy;
            size_t p = (size_t)z * (DIM * DIM) + (size_t)y * DIM + xx;
            f32x4 a = acc[mf][nf];
            #pragma unroll
            for (int r = 0; r < 4; ++r) {
                int o = mh * 64 + mf * 16 + krow * 4 + r;
                out[(size_t)(b * COUT + o) * SP + p] = a[r] + bv[r];
            }
        }
    }
}

// ---------------------------------------------------------------------------
extern "C" void kernel_launch(void* const* d_in, const int* in_sizes, int n_in,
                              void* d_out, int out_size, void* d_ws, size_t ws_size,
                              hipStream_t stream) {
    const float* x       = (const float*)d_in[0];
    const float* style   = (const float*)d_in[1];
    const float* weight  = (const float*)d_in[2];
    const float* bias    = (const float*)d_in[3];
    const float* w_scale = (const float*)d_in[4];
    const float* b_scale = (const float*)d_in[5];
    const float* w_shift = (const float*)d_in[6];
    const float* b_shift = (const float*)d_in[7];
    const float* w_kmod  = (const float*)d_in[8];
    const float* b_kmod  = (const float*)d_in[9];
    float* out = (float*)d_out;
    float* ws  = (float*)d_ws;

    unsigned short* xpb  = (unsigned short*)((char*)d_ws + XPB_OFF);
    unsigned short* wsbf = (unsigned short*)((char*)d_ws + WSBF_OFF);

    {
        int waves = NB * (2 * CIN + CIN * TAPS);
        int blocks = (waves + 3) / 4;
        modparams_kernel<<<blocks, 256, 0, stream>>>(style, w_scale, b_scale,
                                                     w_shift, b_shift, w_kmod, b_kmod, ws);
    }
    {
        int n = NB * 27 * 8 * 128 * 8;
        build_wsbf2_kernel<<<(n + 255) / 256, 256, 0, stream>>>(weight, ws, wsbf);
    }
    {
        int blocks = NB * 50 * 50;
        pad_kernel<<<blocks, 256, 0, stream>>>(x, ws, xpb);
    }
    {
        int blocks = NB * 432;   // 1728
        conv_fast18_kernel<<<blocks, 512, 0, stream>>>(xpb, wsbf, bias, out);
    }
}

// Round 21
// 216.841 us; speedup vs baseline: 1.6077x; 1.6077x over previous
//
#include <hip/hip_runtime.h>
#include <hip/hip_bf16.h>

// Problem constants
#define NB   4
#define CIN  64
#define COUT 128
#define SDIM 512
#define DIM  48
#define SP   (DIM*DIM*DIM)   // 110592
#define TAPS 27
#define KTOT (CIN*TAPS)      // 1728

// ---- small-param layout (float offsets at base of ws) ----
#define WS_S1P 0                         // [NB*CIN]       1+scale
#define WS_SH  (WS_S1P + NB*CIN)         // [NB*CIN]       shift
#define WS_KM  (WS_SH + NB*CIN)          // [NB*CIN*TAPS]  kmod
// ---- fast path byte offsets ----
#define XPB_OFF   32768ull                        // padded mod x (bf16 channel-last), 64 MB
#define XPB_BYTES (4ull*125000ull*64ull*2ull)     // 64,000,000
#define WSBF_OFF  (XPB_OFF + XPB_BYTES)
#define WSBF_BYTES ((size_t)NB*27*8*128*8*2)      // 1,769,472

typedef __attribute__((ext_vector_type(4))) float  f32x4;
typedef __attribute__((ext_vector_type(8))) short  short8;
typedef __attribute__((ext_vector_type(8))) unsigned short u16x8;

__device__ __forceinline__ void gld16(const void* g, void* l) {
    __builtin_amdgcn_global_load_lds(
        (const __attribute__((address_space(1))) void*)g,
        (__attribute__((address_space(3))) void*)l, 16, 0, 0);
}

// ---------------------------------------------------------------------------
// Kernel A: style dot products. One wave per row. float4-vectorized loads.
// ---------------------------------------------------------------------------
__global__ void modparams_kernel(const float* __restrict__ style,
                                 const float* __restrict__ w_scale, const float* __restrict__ b_scale,
                                 const float* __restrict__ w_shift, const float* __restrict__ b_shift,
                                 const float* __restrict__ w_kmod,  const float* __restrict__ b_kmod,
                                 float* __restrict__ ws) {
    const int ROWS = 2 * CIN + CIN * TAPS;  // 1856
    int gwave = (blockIdx.x * blockDim.x + threadIdx.x) >> 6;
    int lane  = threadIdx.x & 63;
    if (gwave >= NB * ROWS) return;
    int b = gwave / ROWS;
    int r = gwave % ROWS;

    const float* srow = style + b * SDIM;
    const float* mrow;
    float bias, add = 0.f;
    float* dst;
    if (r < CIN) {
        mrow = w_scale + r * SDIM; bias = b_scale[r];
        dst = ws + WS_S1P + b * CIN + r; add = 1.f;          // store (1+scale)
    } else if (r < 2 * CIN) {
        int c = r - CIN;
        mrow = w_shift + c * SDIM; bias = b_shift[c];
        dst = ws + WS_SH + b * CIN + c;
    } else {
        int t = r - 2 * CIN;
        mrow = w_kmod + t * SDIM; bias = b_kmod[t];
        dst = ws + WS_KM + b * (CIN * TAPS) + t;
    }

    const float4* s4 = (const float4*)srow;
    const float4* m4 = (const float4*)mrow;
    float acc = 0.f;
    #pragma unroll
    for (int k4 = 0; k4 < 2; ++k4) {
        float4 sv = s4[lane + k4 * 64];
        float4 mv = m4[lane + k4 * 64];
        acc += sv.x * mv.x + sv.y * mv.y + sv.z * mv.z + sv.w * mv.w;
    }
    #pragma unroll
    for (int off = 32; off; off >>= 1) acc += __shfl_down(acc, off);
    if (lane == 0) *dst = acc + bias + add;
}

// ---------------------------------------------------------------------------
// WSBF2[(((b*27+tau)*8 + s)*128 + o)*8 + j] = bf16(weight[o, c=s*8+j, tau] *
//                                                  (1 + kmod[b, c, tau]))
// ---------------------------------------------------------------------------
__global__ void build_wsbf2_kernel(const float* __restrict__ weight, const float* __restrict__ ws,
                                   unsigned short* __restrict__ wsbf) {
    int d = blockIdx.x * blockDim.x + threadIdx.x;
    if (d >= NB * 27 * 8 * 128 * 8) return;
    int j   = d & 7;
    int o   = (d >> 3) & 127;
    int s   = (d >> 10) & 7;
    int rem = d >> 13;
    int tau = rem % 27;
    int b   = rem / 27;
    int c   = s * 8 + j;
    float wm = weight[(o * CIN + c) * TAPS + tau] * (1.f + ws[WS_KM + b * KTOT + c * TAPS + tau]);
    __hip_bfloat16 h = __float2bfloat16(wm);
    wsbf[d] = *(unsigned short*)&h;
}

// ---------------------------------------------------------------------------
// Pad + modulate + transpose to channel-last bf16: xpb[b][pz][py][px][c]
// float4-vectorized x reads.
// ---------------------------------------------------------------------------
__global__ __launch_bounds__(256) void pad_kernel(const float* __restrict__ x,
                                                  const float* __restrict__ ws,
                                                  unsigned short* __restrict__ xpb) {
    __shared__ unsigned short lxm[48 * 72];   // [w][c], row stride 144B (16B-aligned)
    int bid = blockIdx.x;
    int py = bid % 50;
    int pz = (bid / 50) % 50;
    int b  = bid / 2500;
    int t = threadIdx.x;
    bool interior = (pz >= 1 && pz <= 48 && py >= 1 && py <= 48);
    if (interior) {
        int z = pz - 1, y = py - 1;
        const float* xr = x + (size_t)b * CIN * SP + (size_t)z * (DIM*DIM) + y * DIM;
        #pragma unroll
        for (int it = 0; it < 3; ++it) {
            int u = it * 256 + t;                 // 768 float4 units
            int c  = u / 12;
            int w4 = (u - c * 12) * 4;
            float4 v = *(const float4*)(xr + (size_t)c * SP + w4);
            float s1 = ws[WS_S1P + b * CIN + c];
            float sh = ws[WS_SH  + b * CIN + c];
            float m0 = v.x * s1 + sh, m1 = v.y * s1 + sh;
            float m2 = v.z * s1 + sh, m3 = v.w * s1 + sh;
            __hip_bfloat16 h0 = __float2bfloat16(m0);
            __hip_bfloat16 h1 = __float2bfloat16(m1);
            __hip_bfloat16 h2 = __float2bfloat16(m2);
            __hip_bfloat16 h3 = __float2bfloat16(m3);
            lxm[(w4 + 0) * 72 + c] = *(unsigned short*)&h0;
            lxm[(w4 + 1) * 72 + c] = *(unsigned short*)&h1;
            lxm[(w4 + 2) * 72 + c] = *(unsigned short*)&h2;
            lxm[(w4 + 3) * 72 + c] = *(unsigned short*)&h3;
        }
    }
    __syncthreads();
    unsigned short* dst = xpb + (size_t)b * 8000000ull + ((size_t)pz * 2500 + py * 50) * 64;
    #pragma unroll
    for (int it = 0; it < 2; ++it) {
        int i8 = it * 256 + t;
        if (i8 < 400) {
            int w  = i8 >> 3;          // padded px
            int c8 = (i8 & 7) * 8;
            u16x8 v = {};
            if (interior && w >= 1 && w <= 48)
                v = *(const u16x8*)&lxm[(w - 1) * 72 + c8];
            *(u16x8*)(dst + i8 * 8) = v;
        }
    }
}

// ---------------------------------------------------------------------------
// Conv v15 (R17, best measured: 176 us, MfmaUtil 50.7): 512 thr, 4z x 8y x 8x,
// pos-major XOR halo staged once via gld16, pinned-A asm pipeline (tap-ahead
// double buffer, vmcnt(8)), cross-tap B double-buffer, zero-VALU B addressing
// via precomputed XOR bases + compile-time ds offset immediates, no setprio.
// ---------------------------------------------------------------------------
#define HALOPOS 600            // 6*10*10
#define BH_CHUNKS (HALOPOS*8)  // 4800 16B-chunks

#define GLD16R(dst, p, OFF)                                                    \
    asm volatile("global_load_dwordx4 %0, %1, off offset:" #OFF                \
                 : "=v"(dst) : "v"(p) : "memory")

#define ISSUEA(buf, tap_) do {                                                 \
    const unsigned short* _p0 = wA + (size_t)(tap_) * 8192;                    \
    const unsigned short* _p1 = _p0 + 4096;                                    \
    GLD16R(buf[0], _p0, 0);   GLD16R(buf[1], _p0, 256);                        \
    GLD16R(buf[2], _p0, 512); GLD16R(buf[3], _p0, 768);                        \
    GLD16R(buf[4], _p1, 0);   GLD16R(buf[5], _p1, 256);                        \
    GLD16R(buf[6], _p1, 512); GLD16R(buf[7], _p1, 768);                        \
} while (0)

// tap delta within halo position space (compile-time when unrolled)
#define DLT(t_) (((t_) / 9) * 100 + (((t_) / 3) % 3) * 10 + ((t_) % 3))

// read 4 B fragments for tap t_ from precomputed bases: zero VALU per read.
// byte addr = bb[(D)&7] + D*128, D = DLT(t_) + nf*20 (all compile-time).
#define BREADX(dst, bb, t_) do {                                               \
    _Pragma("unroll")                                                          \
    for (int nf = 0; nf < 4; ++nf) {                                           \
        const int D = DLT(t_) + nf * 20;                                       \
        dst[nf] = *(const short8*)((const char*)Bh + bb[D & 7] + D * 128);     \
    }                                                                          \
} while (0)

// one tap, software-pipelined B, no setprio:
//   bcur = ch0 frags of tap t (read during tap t-1); bnxt gets tap t+1's ch0.
#define TAPP(cur, nxt, bcur, bnxt, t_) do {                                    \
    if ((t_) < 26) {                                                           \
        ISSUEA(nxt, (t_) + 1);                                                 \
        asm volatile("s_waitcnt vmcnt(8)" ::: "memory");                       \
    } else {                                                                   \
        asm volatile("s_waitcnt vmcnt(0)" ::: "memory");                       \
    }                                                                          \
    __builtin_amdgcn_sched_barrier(0);                                         \
    BREADX(bC1, bb1, t_);                  /* ch1 frags, used in burst1 */     \
    _Pragma("unroll")                                                          \
    for (int mf = 0; mf < 4; ++mf)                                             \
        _Pragma("unroll")                                                      \
        for (int nf = 0; nf < 4; ++nf)                                         \
            acc[mf][nf] = __builtin_amdgcn_mfma_f32_16x16x32_bf16(             \
                cur[mf], bcur[nf], acc[mf][nf], 0, 0, 0);                      \
    if ((t_) < 26) BREADX(bnxt, bb0, (t_) + 1);  /* next tap ch0, early */     \
    _Pragma("unroll")                                                          \
    for (int mf = 0; mf < 4; ++mf)                                             \
        _Pragma("unroll")                                                      \
        for (int nf = 0; nf < 4; ++nf)                                         \
            acc[mf][nf] = __builtin_amdgcn_mfma_f32_16x16x32_bf16(             \
                cur[4 + mf], bC1[nf], acc[mf][nf], 0, 0, 0);                   \
} while (0)

__global__ __launch_bounds__(512, 2) void conv_fast15_kernel(
    const unsigned short* __restrict__ xpb,
    const unsigned short* __restrict__ wsbf,
    const float* __restrict__ bias,
    float* __restrict__ out)
{
    __shared__ unsigned short Bh[HALOPOS * 64];   // 76,800 B

    const int t    = threadIdx.x;
    const int lane = t & 63;
    const int wid  = t >> 6;        // 0..7
    const int wz   = wid & 3;       // z-plane
    const int mh   = wid >> 2;      // M half (0/1)

    // XCD-aware bijective swizzle: 1728 = 8 * 216
    int bid0 = blockIdx.x;
    int bid  = (bid0 & 7) * 216 + (bid0 >> 3);
    int tile = bid % 432;
    int b    = bid / 432;
    int tx = tile % 6;
    int ty = (tile / 6) % 6;
    int tz = tile / 36;             // 0..11
    int x0 = tx * 8, y0 = ty * 8, z0 = tz * 4;

    const unsigned short* xb = xpb + (size_t)b * 8000000ull;
    const unsigned short* wb = wsbf + (size_t)b * (27 * 8 * 128 * 8);

    const int col  = lane & 15;
    const int krow = lane >> 4;   // 0..3
    const int cy   = col >> 3;    // 0..1
    const int cx   = col & 7;     // 0..7
    const int pbase = wz * 100 + cy * 10 + cx;

    // per-lane A base (shorts): slot = ch*4 + krow, o = mh*64 + mf*16 + col
    const unsigned short* wA = wb + (size_t)(krow * 128 + mh * 64 + col) * 8;

    // precomputed B base byte-offsets: bb[j] for D&7 == j (ch0 and ch1)
    unsigned bb0[8], bb1[8];
    #pragma unroll
    for (int j = 0; j < 8; ++j) {
        int pj = (pbase + j) & 7;
        bb0[j] = (unsigned)(pbase * 128 + ((krow ^ pj) << 4));
        bb1[j] = (unsigned)(pbase * 128 + (((4 + krow) ^ pj) << 4));
    }

    f32x4 acc[4][4] = {};
    short8 a0[8], a1[8];
    short8 bX[4], bY[4], bC1[4];

    ISSUEA(a0, 0);   // tap-0 A in flight; drained by the barrier below

    // ---- stage B halo once: gld16, pre-swizzled global source (R6 layout) --
    #pragma unroll
    for (int it = 0; it < 10; ++it) {
        int i = it * 512 + t;
        if (i < BH_CHUNKS) {
            int pidx = i >> 3;
            int slot = i & 7;
            int hx = pidx % 10;
            int hy = (pidx / 10) % 10;
            int hz = pidx / 100;
            int srcslot = slot ^ (pidx & 7);
            const unsigned short* g = xb
                + ((size_t)((z0 + hz) * 2500 + (y0 + hy) * 50 + (x0 + hx))) * 64
                + srcslot * 8;
            gld16(g, &Bh[i * 8]);
        }
    }
    __syncthreads();   // halo + tap-0 A staged; the ONLY block-wide barrier

    BREADX(bX, bb0, 0);   // prologue: tap-0 ch0 fragments

    #pragma unroll
    for (int tp = 0; tp < 26; tp += 2) {
        TAPP(a0, a1, bX, bY, tp);
        TAPP(a1, a0, bY, bX, tp + 1);
    }
    TAPP(a0, a1, bX, bY, 26);

    // ---- epilogue: + bias, store ----
    int z  = z0 + wz;
    int xx = x0 + cx;
    #pragma unroll
    for (int mf = 0; mf < 4; ++mf) {
        f32x4 bv = *(const f32x4*)&bias[mh * 64 + mf * 16 + krow * 4];
        #pragma unroll
        for (int nf = 0; nf < 4; ++nf) {
            int y = y0 + nf * 2 + cy;
            size_t p = (size_t)z * (DIM * DIM) + (size_t)y * DIM + xx;
            f32x4 a = acc[mf][nf];
            #pragma unroll
            for (int r = 0; r < 4; ++r) {
                int o = mh * 64 + mf * 16 + krow * 4 + r;
                out[(size_t)(b * COUT + o) * SP + p] = a[r] + bv[r];
            }
        }
    }
}

// ---------------------------------------------------------------------------
extern "C" void kernel_launch(void* const* d_in, const int* in_sizes, int n_in,
                              void* d_out, int out_size, void* d_ws, size_t ws_size,
                              hipStream_t stream) {
    const float* x       = (const float*)d_in[0];
    const float* style   = (const float*)d_in[1];
    const float* weight  = (const float*)d_in[2];
    const float* bias    = (const float*)d_in[3];
    const float* w_scale = (const float*)d_in[4];
    const float* b_scale = (const float*)d_in[5];
    const float* w_shift = (const float*)d_in[6];
    const float* b_shift = (const float*)d_in[7];
    const float* w_kmod  = (const float*)d_in[8];
    const float* b_kmod  = (const float*)d_in[9];
    float* out = (float*)d_out;
    float* ws  = (float*)d_ws;

    unsigned short* xpb  = (unsigned short*)((char*)d_ws + XPB_OFF);
    unsigned short* wsbf = (unsigned short*)((char*)d_ws + WSBF_OFF);

    {
        int waves = NB * (2 * CIN + CIN * TAPS);
        int blocks = (waves + 3) / 4;
        modparams_kernel<<<blocks, 256, 0, stream>>>(style, w_scale, b_scale,
                                                     w_shift, b_shift, w_kmod, b_kmod, ws);
    }
    {
        int n = NB * 27 * 8 * 128 * 8;
        build_wsbf2_kernel<<<(n + 255) / 256, 256, 0, stream>>>(weight, ws, wsbf);
    }
    {
        int blocks = NB * 50 * 50;
        pad_kernel<<<blocks, 256, 0, stream>>>(x, ws, xpb);
    }
    {
        int blocks = NB * 432;   // 1728
        conv_fast15_kernel<<<blocks, 512, 0, stream>>>(xpb, wsbf, bias, out);
    }
}